// Round 7
// baseline (58.327 us; speedup 1.0000x reference)
//
#include <hip/hip_runtime.h>

#define NB 8
#define NC 64
#define NH 256
#define NW 256
#define HW (NH*NW)
#define NFH 64
#define NFW 64
#define FHW (NFH*NFW)
#define NS 256
#define PPB 1024                 // pixels per block
#define NPB (HW/PPB)             // 64 pixel-blocks per image
#define NG 4                     // channel groups
#define CPG (NC/NG)              // 16 channels per group
#define NMAIN (NB*NPB*NG)        // 2048 role-A blocks
#define NRB (NB*NPB)             // 512 role-B blocks

typedef float f32x4 __attribute__((ext_vector_type(4)));

// ---------------- K1: fused streaming kernel, 2560 blocks, split roles ----------------
// blocks [0, NMAIN): role A — 16-channel partial segment sums of input (NT loads).
// blocks [NMAIN, NMAIN+NRB): role B — self-computes the <=3 fmean rows its pixels
//   touch (from feature), then counts + bilinear feature-mean segment sums.
__global__ __launch_bounds__(256) void
main_k(const float* __restrict__ input,
       const float* __restrict__ feature,
       const int* __restrict__ sp,
       float* __restrict__ part1,     // [NMAIN][NS]
       float* __restrict__ part2,     // [NRB][NS]
       float* __restrict__ partc,     // [NRB][NS]
       unsigned* __restrict__ counter) {
  __shared__ float s_bins[NS];
  __shared__ float s_fb[NS];
  __shared__ unsigned s_cnt[NS];
  __shared__ float s_frow[3][NFW];   // the (<=3) fmean rows this block needs

  const int bid = blockIdx.x;
  const int tid = threadIdx.x;
  if (bid == 0 && tid == 0) *counter = 0u;   // arm finalize's last-block gate

  if (bid < NMAIN) {
    // ----- role A -----
    const int g  = bid & (NG - 1);
    const int pb = (bid >> 2) & (NPB - 1);
    const int b  = bid >> 8;

    s_bins[tid] = 0.f;
    __syncthreads();

    const int p0 = pb * PPB + tid * 4;
    const float* ib = input + (size_t)(b * NC + g * CPG) * HW + p0;
    f32x4 acc = (f32x4)(0.f);
    #pragma unroll
    for (int c = 0; c < CPG; ++c) {
      f32x4 v = __builtin_nontemporal_load(
          reinterpret_cast<const f32x4*>(ib + (size_t)c * HW));
      acc += v;
    }
    const int4 idv = *reinterpret_cast<const int4*>(sp + (size_t)b * HW + p0);
    const float s = 1.0f / NC;
    atomicAdd(&s_bins[idv.x], acc.x * s);
    atomicAdd(&s_bins[idv.y], acc.y * s);
    atomicAdd(&s_bins[idv.z], acc.z * s);
    atomicAdd(&s_bins[idv.w], acc.w * s);
    __syncthreads();

    part1[(size_t)bid * NS + tid] = s_bins[tid];
  } else {
    // ----- role B -----
    const int r  = bid - NMAIN;       // 0..511
    const int b  = r >> 6;
    const int pb = r & (NPB - 1);

    const int h0    = pb * 4;                       // first of 4 input rows
    const int y0min = (h0 * (NFH - 1)) / (NH - 1);  // lowest fmean row touched

    s_fb[tid] = 0.f;
    s_cnt[tid] = 0u;
    if (tid < 192) s_frow[tid >> 6][tid & 63] = 0.f;
    __syncthreads();

    // self-compute 3 fmean rows: thread = (channel-quarter q, px)
    {
      const int px = tid & 63;
      const int q  = tid >> 6;                      // 0..3
      const int r0 = min(y0min,     NFH - 1);
      const int r1 = min(y0min + 1, NFH - 1);
      const int r2 = min(y0min + 2, NFH - 1);
      const float* fb = feature + (size_t)(b * NC + q * 16) * FHW;
      float a0 = 0.f, a1 = 0.f, a2 = 0.f;
      #pragma unroll
      for (int c = 0; c < 16; ++c) {
        const float* fc = fb + (size_t)c * FHW;
        a0 += fc[r0 * NFW + px];
        a1 += fc[r1 * NFW + px];
        a2 += fc[r2 * NFW + px];
      }
      const float s = 1.0f / NC;
      atomicAdd(&s_frow[0][px], a0 * s);
      atomicAdd(&s_frow[1][px], a1 * s);
      atomicAdd(&s_frow[2][px], a2 * s);
    }
    __syncthreads();

    const int p0 = pb * PPB + tid * 4;
    const int4 idv = *reinterpret_cast<const int4*>(sp + (size_t)b * HW + p0);
    const int ids[4] = {idv.x, idv.y, idv.z, idv.w};

    const int h = p0 >> 8;            // row shared by the thread's 4 pixels
    const float yd = (float)h * (63.0f / 255.0f);
    const int y0 = (int)yd;
    const float wy = yd - (float)y0;
    const int y1 = min(y0 + 1, NFH - 1);
    const float* row0 = s_frow[y0 - y0min];
    const float* row1 = s_frow[y1 - y0min];

    #pragma unroll
    for (int i = 0; i < 4; ++i) {
      const int w = (p0 & 255) + i;
      const float xd = (float)w * (63.0f / 255.0f);
      const int x0 = (int)xd;
      const float wx = xd - (float)x0;
      const int x1 = min(x0 + 1, NFW - 1);
      float v0 = row0[x0] * (1.f - wy) + row1[x0] * wy;
      float v1 = row0[x1] * (1.f - wy) + row1[x1] * wy;
      float fv = v0 * (1.f - wx) + v1 * wx;
      atomicAdd(&s_fb[ids[i]], fv);
      atomicAdd(&s_cnt[ids[i]], 1u);
    }
    __syncthreads();

    part2[(size_t)r * NS + tid] = s_fb[tid];
    partc[(size_t)r * NS + tid] = (float)s_cnt[tid];
  }
}

// ---------------- K2: reduce partials -> means -> S x S loss; last block finishes ----
__global__ __launch_bounds__(256) void
finalize_k(const float* __restrict__ part1,
           const float* __restrict__ part2,
           const float* __restrict__ partc,
           const int* __restrict__ num,
           float* __restrict__ partial,
           unsigned* __restrict__ counter,
           float* __restrict__ out) {
  __shared__ float m1[NS];
  __shared__ float m2[NS];
  __shared__ float red[256];
  const int b = blockIdx.x;
  const int j = threadIdx.x;

  float s1 = 0.f;
  const float* p1 = part1 + (size_t)b * 256 * NS + j;
  #pragma unroll 8
  for (int t = 0; t < 256; ++t) s1 += p1[(size_t)t * NS];

  float s2 = 0.f, c = 0.f;
  const float* p2 = part2 + (size_t)b * 64 * NS + j;
  const float* pc = partc + (size_t)b * 64 * NS + j;
  #pragma unroll 8
  for (int t = 0; t < 64; ++t) { s2 += p2[(size_t)t * NS]; c += pc[(size_t)t * NS]; }

  const int nb = num[b];
  float v1 = 0.f, v2 = 0.f;
  if (j < nb && c > 0.f) {
    float invc = 1.0f / c;
    v1 = s1 * invc;
    v2 = s2 * invc;
  }
  m1[j] = v1; m2[j] = v2;
  __syncthreads();

  float accum = 0.f;
  #pragma unroll 8
  for (int k = 0; k < NS; ++k) {
    accum += fabsf(fabsf(v1 - m1[k]) - fabsf(v2 - m2[k]));
  }
  red[j] = accum;
  __syncthreads();
  for (int st = 128; st > 0; st >>= 1) {
    if (j < st) red[j] += red[j + st];
    __syncthreads();
  }

  if (j == 0) {
    atomicExch(&partial[b], red[0]);        // device-scope coherent store
    __threadfence();
    unsigned old = atomicAdd(counter, 1u);
    if (old == NB - 1) {                    // last image block finishes the loss
      __threadfence();
      float sAll = 0.f;
      #pragma unroll
      for (int i = 0; i < NB; ++i) sAll += atomicAdd(&partial[i], 0.0f);
      out[0] = sAll / (float)(NB * NS * NS);
      *counter = 0u;
    }
  }
}

extern "C" void kernel_launch(void* const* d_in, const int* in_sizes, int n_in,
                              void* d_out, int out_size, void* d_ws, size_t ws_size,
                              hipStream_t stream) {
  const float* input   = (const float*)d_in[0];   // [8,64,256,256] f32
  const float* feature = (const float*)d_in[1];   // [8,64,64,64]   f32
  const int*   sp      = (const int*)d_in[2];     // [8,1,256,256]  int32
  const int*   num     = (const int*)d_in[3];     // [8]            int32
  float* out = (float*)d_out;

  float* ws      = (float*)d_ws;
  float*    part1   = ws;                                   // 524288 floats
  float*    part2   = part1 + (size_t)NMAIN * NS;           // 131072
  float*    partc   = part2 + (size_t)NRB * NS;             // 131072
  float*    partial = partc + (size_t)NRB * NS;             // 8
  unsigned* counter = (unsigned*)(partial + 8);             // 1

  main_k<<<NMAIN + NRB, 256, 0, stream>>>(input, feature, sp, part1, part2, partc, counter);
  finalize_k<<<NB, 256, 0, stream>>>(part1, part2, partc, num, partial, counter, out);
}

// Round 8
// 53.082 us; speedup vs baseline: 1.0988x; 1.0988x over previous
//
#include <hip/hip_runtime.h>

#define NB 8
#define NC 64
#define NH 256
#define NW 256
#define HW (NH*NW)
#define NFH 64
#define NFW 64
#define FHW (NFH*NFW)
#define NS 256
#define PPA 2048                 // pixels per role-A block (2 dense 1024-px windows)
#define NPA (HW/PPA)             // 32 pixel-blocks per image (role A)
#define PPB 1024                 // pixels per role-B block
#define NPB (HW/PPB)             // 64 pixel-blocks per image (role B)
#define NG 4                     // channel groups
#define CPG (NC/NG)              // 16 channels per group
#define NMAIN (NB*NPA*NG)        // 1024 role-A blocks
#define NRB (NB*NPB)             // 512 role-B blocks

typedef float f32x4 __attribute__((ext_vector_type(4)));

// ---------------- K1: fused streaming kernel, 1536 blocks, split roles ----------------
// blocks [0, NMAIN): role A — 16-channel partial segment sums of input, 8 px/thread.
// blocks [NMAIN, NMAIN+NRB): role B — self-computes the <=3 fmean rows its pixels
//   touch (from feature), then counts + bilinear feature-mean segment sums.
__global__ __launch_bounds__(256) void
main_k(const float* __restrict__ input,
       const float* __restrict__ feature,
       const int* __restrict__ sp,
       float* __restrict__ part1,     // [NMAIN][NS]
       float* __restrict__ part2,     // [NRB][NS]
       float* __restrict__ partc,     // [NRB][NS]
       unsigned* __restrict__ counter) {
  __shared__ float s_bins[NS];
  __shared__ float s_fb[NS];
  __shared__ unsigned s_cnt[NS];
  __shared__ float s_frow[3][NFW];   // the (<=3) fmean rows a role-B block needs

  const int bid = blockIdx.x;
  const int tid = threadIdx.x;
  if (bid == 0 && tid == 0) *counter = 0u;   // arm finalize's last-block gate

  if (bid < NMAIN) {
    // ----- role A: 2048 px x 16 channels, two dense 1024-px windows -----
    const int g  = bid & (NG - 1);
    const int pb = (bid >> 2) & (NPA - 1);
    const int b  = bid >> 7;

    s_bins[tid] = 0.f;
    __syncthreads();

    const int base = pb * PPA;
    const float* ib = input + (size_t)(b * NC + g * CPG) * HW + base;
    const int o = tid * 4;
    f32x4 accA = (f32x4)(0.f);
    f32x4 accB = (f32x4)(0.f);
    #pragma unroll
    for (int c = 0; c < CPG; ++c) {
      accA += *reinterpret_cast<const f32x4*>(ib + (size_t)c * HW + o);
      accB += *reinterpret_cast<const f32x4*>(ib + (size_t)c * HW + 1024 + o);
    }
    const int4 idvA = *reinterpret_cast<const int4*>(sp + (size_t)b * HW + base + o);
    const int4 idvB = *reinterpret_cast<const int4*>(sp + (size_t)b * HW + base + 1024 + o);
    const float s = 1.0f / NC;
    atomicAdd(&s_bins[idvA.x], accA.x * s);
    atomicAdd(&s_bins[idvA.y], accA.y * s);
    atomicAdd(&s_bins[idvA.z], accA.z * s);
    atomicAdd(&s_bins[idvA.w], accA.w * s);
    atomicAdd(&s_bins[idvB.x], accB.x * s);
    atomicAdd(&s_bins[idvB.y], accB.y * s);
    atomicAdd(&s_bins[idvB.z], accB.z * s);
    atomicAdd(&s_bins[idvB.w], accB.w * s);
    __syncthreads();

    part1[(size_t)bid * NS + tid] = s_bins[tid];
  } else {
    // ----- role B -----
    const int r  = bid - NMAIN;       // 0..511
    const int b  = r >> 6;
    const int pb = r & (NPB - 1);

    const int h0    = pb * 4;                       // first of 4 input rows
    const int y0min = (h0 * (NFH - 1)) / (NH - 1);  // lowest fmean row touched

    s_fb[tid] = 0.f;
    s_cnt[tid] = 0u;
    if (tid < 192) s_frow[tid >> 6][tid & 63] = 0.f;
    __syncthreads();

    // self-compute 3 fmean rows: thread = (channel-quarter q, px)
    {
      const int px = tid & 63;
      const int q  = tid >> 6;                      // 0..3
      const int r0 = min(y0min,     NFH - 1);
      const int r1 = min(y0min + 1, NFH - 1);
      const int r2 = min(y0min + 2, NFH - 1);
      const float* fb = feature + (size_t)(b * NC + q * 16) * FHW;
      float a0 = 0.f, a1 = 0.f, a2 = 0.f;
      #pragma unroll
      for (int c = 0; c < 16; ++c) {
        const float* fc = fb + (size_t)c * FHW;
        a0 += fc[r0 * NFW + px];
        a1 += fc[r1 * NFW + px];
        a2 += fc[r2 * NFW + px];
      }
      const float sc = 1.0f / NC;
      atomicAdd(&s_frow[0][px], a0 * sc);
      atomicAdd(&s_frow[1][px], a1 * sc);
      atomicAdd(&s_frow[2][px], a2 * sc);
    }
    __syncthreads();

    const int p0 = pb * PPB + tid * 4;
    const int4 idv = *reinterpret_cast<const int4*>(sp + (size_t)b * HW + p0);
    const int ids[4] = {idv.x, idv.y, idv.z, idv.w};

    const int h = p0 >> 8;            // row shared by the thread's 4 pixels
    const float yd = (float)h * (63.0f / 255.0f);
    const int y0 = (int)yd;
    const float wy = yd - (float)y0;
    const int y1 = min(y0 + 1, NFH - 1);
    const float* row0 = s_frow[y0 - y0min];
    const float* row1 = s_frow[y1 - y0min];

    #pragma unroll
    for (int i = 0; i < 4; ++i) {
      const int w = (p0 & 255) + i;
      const float xd = (float)w * (63.0f / 255.0f);
      const int x0 = (int)xd;
      const float wx = xd - (float)x0;
      const int x1 = min(x0 + 1, NFW - 1);
      float v0 = row0[x0] * (1.f - wy) + row1[x0] * wy;
      float v1 = row0[x1] * (1.f - wy) + row1[x1] * wy;
      float fv = v0 * (1.f - wx) + v1 * wx;
      atomicAdd(&s_fb[ids[i]], fv);
      atomicAdd(&s_cnt[ids[i]], 1u);
    }
    __syncthreads();

    part2[(size_t)r * NS + tid] = s_fb[tid];
    partc[(size_t)r * NS + tid] = (float)s_cnt[tid];
  }
}

// ---------------- K2: reduce partials -> means -> S x S loss; last block finishes ----
__global__ __launch_bounds__(256) void
finalize_k(const float* __restrict__ part1,
           const float* __restrict__ part2,
           const float* __restrict__ partc,
           const int* __restrict__ num,
           float* __restrict__ partial,
           unsigned* __restrict__ counter,
           float* __restrict__ out) {
  __shared__ float m1[NS];
  __shared__ float m2[NS];
  __shared__ float red[256];
  const int b = blockIdx.x;
  const int j = threadIdx.x;

  float s1 = 0.f;
  const float* p1 = part1 + (size_t)b * (NMAIN / NB) * NS + j;   // 128 blocks/image
  #pragma unroll 8
  for (int t = 0; t < NMAIN / NB; ++t) s1 += p1[(size_t)t * NS];

  float s2 = 0.f, c = 0.f;
  const float* p2 = part2 + (size_t)b * 64 * NS + j;
  const float* pc = partc + (size_t)b * 64 * NS + j;
  #pragma unroll 8
  for (int t = 0; t < 64; ++t) { s2 += p2[(size_t)t * NS]; c += pc[(size_t)t * NS]; }

  const int nb = num[b];
  float v1 = 0.f, v2 = 0.f;
  if (j < nb && c > 0.f) {
    float invc = 1.0f / c;
    v1 = s1 * invc;
    v2 = s2 * invc;
  }
  m1[j] = v1; m2[j] = v2;
  __syncthreads();

  float accum = 0.f;
  #pragma unroll 8
  for (int k = 0; k < NS; ++k) {
    accum += fabsf(fabsf(v1 - m1[k]) - fabsf(v2 - m2[k]));
  }
  red[j] = accum;
  __syncthreads();
  for (int st = 128; st > 0; st >>= 1) {
    if (j < st) red[j] += red[j + st];
    __syncthreads();
  }

  if (j == 0) {
    atomicExch(&partial[b], red[0]);        // device-scope coherent store
    __threadfence();
    unsigned old = atomicAdd(counter, 1u);
    if (old == NB - 1) {                    // last image block finishes the loss
      __threadfence();
      float sAll = 0.f;
      #pragma unroll
      for (int i = 0; i < NB; ++i) sAll += atomicAdd(&partial[i], 0.0f);
      out[0] = sAll / (float)(NB * NS * NS);
      *counter = 0u;
    }
  }
}

extern "C" void kernel_launch(void* const* d_in, const int* in_sizes, int n_in,
                              void* d_out, int out_size, void* d_ws, size_t ws_size,
                              hipStream_t stream) {
  const float* input   = (const float*)d_in[0];   // [8,64,256,256] f32
  const float* feature = (const float*)d_in[1];   // [8,64,64,64]   f32
  const int*   sp      = (const int*)d_in[2];     // [8,1,256,256]  int32
  const int*   num     = (const int*)d_in[3];     // [8]            int32
  float* out = (float*)d_out;

  float* ws      = (float*)d_ws;
  float*    part1   = ws;                                   // NMAIN*NS = 262144 floats
  float*    part2   = part1 + (size_t)NMAIN * NS;           // 131072
  float*    partc   = part2 + (size_t)NRB * NS;             // 131072
  float*    partial = partc + (size_t)NRB * NS;             // 8
  unsigned* counter = (unsigned*)(partial + 8);             // 1

  main_k<<<NMAIN + NRB, 256, 0, stream>>>(input, feature, sp, part1, part2, partc, counter);
  finalize_k<<<NB, 256, 0, stream>>>(part1, part2, partc, num, partial, counter, out);
}